// Round 1
// baseline (199.247 us; speedup 1.0000x reference)
//
#include <hip/hip_runtime.h>
#include <stdint.h>

// NextPanelHead: logits[b,i,j] = P[b,i] . W . P[b,j] + bias
// B=8, N=2048, D=384. Strategy: PW = P@W (GEMM1), logits = PW @ P^T (GEMM2),
// both as fp16-input MFMA GEMMs (threshold 2.38 licenses 16-bit math),
// fp32 accumulate. m97-style 128x128 tile, BK=32, global_load_lds width=16.

#define BATCH 8
#define NSEQ  2048
#define DDIM  384
#define BM 128
#define BN 128
#define BK 32

typedef __attribute__((ext_vector_type(8))) _Float16 half8;
typedef __attribute__((ext_vector_type(4))) _Float16 half4;
typedef __attribute__((ext_vector_type(4))) float    f32x4;

// ---------------- cast P (fp32 -> fp16), vectorized ----------------
__global__ void cast_p_kernel(const float* __restrict__ in,
                              _Float16* __restrict__ out, int n) {
    int i = (blockIdx.x * blockDim.x + threadIdx.x) * 4;
    int stride = gridDim.x * blockDim.x * 4;
    for (; i < n; i += stride) {
        float4 f = *(const float4*)(in + i);
        half4 h;
        h.x = (_Float16)f.x; h.y = (_Float16)f.y;
        h.z = (_Float16)f.z; h.w = (_Float16)f.w;
        *(half4*)(out + i) = h;
    }
}

// ---------------- W[d][e] -> Wt[e][d] fp16 (tiny: 384x384) ----------------
__global__ void transpose_w_kernel(const float* __restrict__ W,
                                   _Float16* __restrict__ Wt) {
    int o = blockIdx.x * blockDim.x + threadIdx.x;  // o = e*384 + d
    if (o < DDIM * DDIM) {
        int e = o / DDIM;
        int d = o - e * DDIM;
        Wt[o] = (_Float16)W[d * DDIM + e];
    }
}

// ---------------- C = A . B^T  (both row-major MxK / NxK, K=384) ----------
// 128x128 tile per block, 256 threads (4 waves in 2x2), each wave 4x4 of
// 16x16x32 f16 MFMA tiles. OUT_HALF: C is fp16 (GEMM1); else fp32 + bias.
template <bool OUT_HALF>
__global__ __launch_bounds__(256, 2) void gemm_bt_kernel(
    const _Float16* __restrict__ A,     // M x 384 row-major
    const _Float16* __restrict__ Bmat,  // N x 384 row-major
    void* __restrict__ Cv,              // M x ldc
    const float* __restrict__ bias_ptr, // nullptr for GEMM1
    long strideA, long strideB, long strideC, int ldc) {
    __shared__ _Float16 As[BM * BK];
    __shared__ _Float16 Bs[BN * BK];

    const _Float16* Ab = A + (size_t)blockIdx.z * strideA
                           + (size_t)blockIdx.y * BM * DDIM;
    const _Float16* Bb = Bmat + (size_t)blockIdx.z * strideB
                              + (size_t)blockIdx.x * BN * DDIM;

    const int tid  = threadIdx.x;
    const int wave = tid >> 6;
    const int lane = tid & 63;
    const int wrow = wave >> 1;   // 0..1
    const int wcol = wave & 1;    // 0..1
    const int lcol = lane & 15;   // col within 16-tile (C) / m or n (A,B)
    const int kq   = lane >> 4;   // 0..3 quad

    f32x4 acc[4][4];
#pragma unroll
    for (int i = 0; i < 4; ++i)
#pragma unroll
        for (int j = 0; j < 4; ++j)
            acc[i][j] = (f32x4){0.f, 0.f, 0.f, 0.f};

    for (int k0 = 0; k0 < DDIM; k0 += BK) {
        // Stage A-tile and B-tile (128x32 fp16 = 8 KB each) via
        // global_load_lds width=16. 512 chunks/tile, 2 per thread.
        // LDS dest = base + lane*16 contiguous (wave-uniform-base rule).
#pragma unroll
        for (int p = 0; p < 2; ++p) {
            int c  = p * 256 + tid;   // 0..511
            int r  = c >> 2;          // tile row 0..127
            int kc = (c & 3) * 8;     // k element offset 0/8/16/24
            __builtin_amdgcn_global_load_lds(
                (const __attribute__((address_space(1))) void*)
                    (Ab + (size_t)r * DDIM + k0 + kc),
                (__attribute__((address_space(3))) void*)(As + c * 8),
                16, 0, 0);
            __builtin_amdgcn_global_load_lds(
                (const __attribute__((address_space(1))) void*)
                    (Bb + (size_t)r * DDIM + k0 + kc),
                (__attribute__((address_space(3))) void*)(Bs + c * 8),
                16, 0, 0);
        }
        __syncthreads();  // drains vmcnt(0) before LDS reads

        half8 af[4], bf[4];
#pragma unroll
        for (int t = 0; t < 4; ++t) {
            int m = wrow * 64 + t * 16 + lcol;
            af[t] = *(const half8*)(As + m * BK + kq * 8);
            int n = wcol * 64 + t * 16 + lcol;
            bf[t] = *(const half8*)(Bs + n * BK + kq * 8);
        }
#pragma unroll
        for (int i = 0; i < 4; ++i)
#pragma unroll
            for (int j = 0; j < 4; ++j)
                acc[i][j] = __builtin_amdgcn_mfma_f32_16x16x32_f16(
                    af[i], bf[j], acc[i][j], 0, 0, 0);
        __syncthreads();  // before next stage overwrites LDS
    }

    // Epilogue. C/D layout: col = lane&15, row = (lane>>4)*4 + reg.
    const size_t row0 = (size_t)blockIdx.y * BM + wrow * 64 + kq * 4;
    const size_t col0 = (size_t)blockIdx.x * BN + wcol * 64 + lcol;
    if (OUT_HALF) {
        _Float16* Cb = (_Float16*)Cv + (size_t)blockIdx.z * strideC;
#pragma unroll
        for (int i = 0; i < 4; ++i)
#pragma unroll
            for (int j = 0; j < 4; ++j)
#pragma unroll
                for (int r = 0; r < 4; ++r)
                    Cb[(row0 + i * 16 + r) * ldc + col0 + j * 16] =
                        (_Float16)acc[i][j][r];
    } else {
        const float bias = bias_ptr[0];
        float* Cb = (float*)Cv + (size_t)blockIdx.z * strideC;
#pragma unroll
        for (int i = 0; i < 4; ++i)
#pragma unroll
            for (int j = 0; j < 4; ++j)
#pragma unroll
                for (int r = 0; r < 4; ++r)
                    Cb[(row0 + i * 16 + r) * ldc + col0 + j * 16] =
                        acc[i][j][r] + bias;
    }
}

extern "C" void kernel_launch(void* const* d_in, const int* in_sizes, int n_in,
                              void* d_out, int out_size, void* d_ws,
                              size_t ws_size, hipStream_t stream) {
    const float* P  = (const float*)d_in[0];  // [8,2048,384]
    const float* W  = (const float*)d_in[1];  // [384,384]
    const float* bp = (const float*)d_in[2];  // [1]
    float* out = (float*)d_out;               // [8,2048,2048]

    // workspace layout (fp16): Pbf 12.6MB | Wt 0.3MB | PW 12.6MB  (~25.5MB)
    _Float16* Ph = (_Float16*)d_ws;
    _Float16* Wt = Ph + (size_t)BATCH * NSEQ * DDIM;
    _Float16* PW = Wt + (size_t)DDIM * DDIM;

    const int nP = BATCH * NSEQ * DDIM;  // 6,291,456 (div by 4)
    cast_p_kernel<<<1024, 256, 0, stream>>>(P, Ph, nP);
    transpose_w_kernel<<<(DDIM * DDIM + 255) / 256, 256, 0, stream>>>(W, Wt);

    // GEMM1: PW[16384 x 384] = Ph[16384 x 384] . Wt^T  (Wt is 384 x 384)
    dim3 g1(DDIM / BN, (BATCH * NSEQ) / BM, 1);  // (3, 128, 1)
    gemm_bt_kernel<true><<<g1, 256, 0, stream>>>(
        Ph, Wt, (void*)PW, nullptr, 0L, 0L, 0L, DDIM);

    // GEMM2 (per batch): out[b] = PW[b] . Ph[b]^T + bias, 2048x2048, K=384
    dim3 g2(NSEQ / BN, NSEQ / BM, BATCH);  // (16, 16, 8)
    gemm_bt_kernel<false><<<g2, 256, 0, stream>>>(
        PW, Ph, (void*)out, bp,
        (long)NSEQ * DDIM, (long)NSEQ * DDIM, (long)NSEQ * NSEQ, NSEQ);
}

// Round 2
// 190.834 us; speedup vs baseline: 1.0441x; 1.0441x over previous
//
#include <hip/hip_runtime.h>
#include <stdint.h>

// NextPanelHead: logits[b,i,j] = P[b,i] . W . P[b,j] + bias
// B=8, N=2048, D=384. PW = P@W (GEMM1), logits = PW @ P^T (GEMM2), fp16 MFMA.
// Round 2: 32x32x16 MFMA (2495 TF ceiling vs 2075, half the instr count),
// BK=64 (half the barrier drains; K=384 -> 6 stages), XOR bank swizzle
// (BK=64 row stride = 128B = 32 banks; unswizzled reads would be 4x slower).

#define BATCH 8
#define NSEQ  2048
#define DDIM  384
#define BM 128
#define BN 128
#define BK 64

typedef __attribute__((ext_vector_type(8)))  _Float16 half8;
typedef __attribute__((ext_vector_type(4)))  _Float16 half4;
typedef __attribute__((ext_vector_type(16))) float    f32x16;

// ---------------- cast P (fp32 -> fp16), vectorized ----------------
__global__ void cast_p_kernel(const float* __restrict__ in,
                              _Float16* __restrict__ out, int n) {
    int i = (blockIdx.x * blockDim.x + threadIdx.x) * 4;
    int stride = gridDim.x * blockDim.x * 4;
    for (; i < n; i += stride) {
        float4 f = *(const float4*)(in + i);
        half4 h;
        h.x = (_Float16)f.x; h.y = (_Float16)f.y;
        h.z = (_Float16)f.z; h.w = (_Float16)f.w;
        *(half4*)(out + i) = h;
    }
}

// ---------------- W[d][e] -> Wt[e][d] fp16 (tiny: 384x384) ----------------
__global__ void transpose_w_kernel(const float* __restrict__ W,
                                   _Float16* __restrict__ Wt) {
    int o = blockIdx.x * blockDim.x + threadIdx.x;  // o = e*384 + d
    if (o < DDIM * DDIM) {
        int e = o / DDIM;
        int d = o - e * DDIM;
        Wt[o] = (_Float16)W[d * DDIM + e];
    }
}

// ---------------- C = A . B^T  (both row-major MxK / NxK, K=384) ----------
// 128x128 tile, 256 threads = 4 waves (2x2), each wave 2x2 of 32x32x16 MFMA.
// LDS layout: row-major BM x BK halves, but chunk c (16B) of row r stored at
// chunk slot (c ^ (r&7)) -> every frag ds_read_b128 hits all 32 banks evenly.
template <bool OUT_HALF>
__global__ __launch_bounds__(256, 2) void gemm_bt_kernel(
    const _Float16* __restrict__ A,     // M x 384 row-major
    const _Float16* __restrict__ Bmat,  // N x 384 row-major
    void* __restrict__ Cv,              // M x ldc
    const float* __restrict__ bias_ptr, // nullptr for GEMM1
    long strideA, long strideB, long strideC, int ldc) {
    __shared__ _Float16 As[BM * BK];  // 16 KB
    __shared__ _Float16 Bs[BN * BK];  // 16 KB

    const _Float16* Ab = A + (size_t)blockIdx.z * strideA
                           + (size_t)blockIdx.y * BM * DDIM;
    const _Float16* Bb = Bmat + (size_t)blockIdx.z * strideB
                              + (size_t)blockIdx.x * BN * DDIM;

    const int tid  = threadIdx.x;
    const int wave = tid >> 6;
    const int lane = tid & 63;
    const int wrow = wave >> 1;   // 0..1
    const int wcol = wave & 1;    // 0..1
    const int lm   = lane & 31;   // row within 32-tile (A) / col (B, C)
    const int hi   = lane >> 5;   // 0..1

    // staging map: slot c = p*256+tid -> row = p*32 + (tid>>3), kslot = tid&7,
    // global chunk = kslot ^ (row&7)  (XOR is self-inverse)
    const int srow = tid >> 3;                       // 0..31
    const int scg  = ((tid & 7) ^ (srow & 7)) * 8;   // global k offset (halves)

    // frag-read bases (bytes): addr = m*128 + ((hi ^ (m&7)) ^ 2s)*16
    const int h0     = (hi ^ (lm & 7)) * 16;
    const int baseA0 = (wrow * 64 + lm) * (BK * 2) + h0;
    const int baseA1 = baseA0 + 32 * (BK * 2);
    const int baseB0 = (wcol * 64 + lm) * (BK * 2) + h0;
    const int baseB1 = baseB0 + 32 * (BK * 2);
    const char* AsB = (const char*)As;
    const char* BsB = (const char*)Bs;

    f32x16 acc[2][2];
#pragma unroll
    for (int i = 0; i < 2; ++i)
#pragma unroll
        for (int j = 0; j < 2; ++j)
#pragma unroll
            for (int r = 0; r < 16; ++r)
                acc[i][j][r] = 0.f;

    for (int k0 = 0; k0 < DDIM; k0 += BK) {
        // Stage A/B tiles (128x64 fp16 = 16 KB each): 1024 16B-chunks per
        // tile, 4 per thread. LDS dest contiguous per wave (base + lane*16).
#pragma unroll
        for (int p = 0; p < 4; ++p) {
            const int r = p * 32 + srow;
            __builtin_amdgcn_global_load_lds(
                (const __attribute__((address_space(1))) void*)
                    (Ab + (size_t)r * DDIM + k0 + scg),
                (__attribute__((address_space(3))) void*)
                    (As + (p * 256 + tid) * 8),
                16, 0, 0);
            __builtin_amdgcn_global_load_lds(
                (const __attribute__((address_space(1))) void*)
                    (Bb + (size_t)r * DDIM + k0 + scg),
                (__attribute__((address_space(3))) void*)
                    (Bs + (p * 256 + tid) * 8),
                16, 0, 0);
        }
        __syncthreads();

#pragma unroll
        for (int s = 0; s < 4; ++s) {  // 4 k-steps of 16
            const int sx = s * 32;
            half8 a0 = *(const half8*)(AsB + (baseA0 ^ sx));
            half8 a1 = *(const half8*)(AsB + (baseA1 ^ sx));
            half8 b0 = *(const half8*)(BsB + (baseB0 ^ sx));
            half8 b1 = *(const half8*)(BsB + (baseB1 ^ sx));
            acc[0][0] = __builtin_amdgcn_mfma_f32_32x32x16_f16(a0, b0, acc[0][0], 0, 0, 0);
            acc[0][1] = __builtin_amdgcn_mfma_f32_32x32x16_f16(a0, b1, acc[0][1], 0, 0, 0);
            acc[1][0] = __builtin_amdgcn_mfma_f32_32x32x16_f16(a1, b0, acc[1][0], 0, 0, 0);
            acc[1][1] = __builtin_amdgcn_mfma_f32_32x32x16_f16(a1, b1, acc[1][1], 0, 0, 0);
        }
        __syncthreads();
    }

    // Epilogue. 32x32 C/D: col = lane&31, row = (reg&3) + 8*(reg>>2) + 4*hi.
    const size_t row_base = (size_t)blockIdx.y * BM + wrow * 64;
    const size_t col_base = (size_t)blockIdx.x * BN + wcol * 64;
    if (OUT_HALF) {
        _Float16* Cb = (_Float16*)Cv + (size_t)blockIdx.z * strideC;
#pragma unroll
        for (int i = 0; i < 2; ++i)
#pragma unroll
            for (int j = 0; j < 2; ++j)
#pragma unroll
                for (int reg = 0; reg < 16; ++reg) {
                    const int rin = (reg & 3) + 8 * (reg >> 2) + 4 * hi;
                    Cb[(row_base + i * 32 + rin) * ldc
                       + col_base + j * 32 + lm] = (_Float16)acc[i][j][reg];
                }
    } else {
        const float bias = bias_ptr[0];
        float* Cb = (float*)Cv + (size_t)blockIdx.z * strideC;
#pragma unroll
        for (int i = 0; i < 2; ++i)
#pragma unroll
            for (int j = 0; j < 2; ++j)
#pragma unroll
                for (int reg = 0; reg < 16; ++reg) {
                    const int rin = (reg & 3) + 8 * (reg >> 2) + 4 * hi;
                    Cb[(row_base + i * 32 + rin) * ldc
                       + col_base + j * 32 + lm] = acc[i][j][reg] + bias;
                }
    }
}

extern "C" void kernel_launch(void* const* d_in, const int* in_sizes, int n_in,
                              void* d_out, int out_size, void* d_ws,
                              size_t ws_size, hipStream_t stream) {
    const float* P  = (const float*)d_in[0];  // [8,2048,384]
    const float* W  = (const float*)d_in[1];  // [384,384]
    const float* bp = (const float*)d_in[2];  // [1]
    float* out = (float*)d_out;               // [8,2048,2048]

    // workspace (fp16): Ph 12.6MB | Wt 0.3MB | PW 12.6MB
    _Float16* Ph = (_Float16*)d_ws;
    _Float16* Wt = Ph + (size_t)BATCH * NSEQ * DDIM;
    _Float16* PW = Wt + (size_t)DDIM * DDIM;

    const int nP = BATCH * NSEQ * DDIM;  // 6,291,456 (div by 4)
    cast_p_kernel<<<1024, 256, 0, stream>>>(P, Ph, nP);
    transpose_w_kernel<<<(DDIM * DDIM + 255) / 256, 256, 0, stream>>>(W, Wt);

    // GEMM1: PW[16384 x 384] = Ph . Wt^T
    dim3 g1(DDIM / BN, (BATCH * NSEQ) / BM, 1);  // (3, 128, 1)
    gemm_bt_kernel<true><<<g1, 256, 0, stream>>>(
        Ph, Wt, (void*)PW, nullptr, 0L, 0L, 0L, DDIM);

    // GEMM2 (per batch): out[b] = PW[b] . Ph[b]^T + bias
    dim3 g2(NSEQ / BN, NSEQ / BM, BATCH);  // (16, 16, 8)
    gemm_bt_kernel<false><<<g2, 256, 0, stream>>>(
        PW, Ph, (void*)out, bp,
        (long)NSEQ * DDIM, (long)NSEQ * DDIM, (long)NSEQ * NSEQ, NSEQ);
}